// Round 4
// 1626.256 us; speedup vs baseline: 2.7979x; 2.7979x over previous
//
#include <hip/hip_runtime.h>

// GraphNetBlock (MeshGraphNets) on MI355X.
// Inputs/outputs are EITHER all-f32 (per reference) or all-bf16 (converted
// dataset). detect_dtype sniffs node_features bit patterns -> flag in d_ws;
// all kernels branch wave-uniformly on it.
// d_out = [new_nodes (50000x128) | new_edges (600000x128)], dtype = input dtype.
//
// R1: replaced 76.8M device-scope f32 atomicAdd (WRITE_SIZE 3.3GB, all pipes
//     idle) with counting-sort CSR + gather aggregation. FAILED on edges.
// R2: edge path restored to R0-identical numerics; still FAILED on edges
//     (0.24) while nodes (downstream of CSR+agg) PASSED.
// R3: ws shrunk 28.8MB->3.2MB (overflow theory); still FAILED on edges
//     (0.27, nondeterministic across rounds). Edge corruption is real but
//     not attributable to any in-bounds analysis of our writes.
// R4: remove all remaining structural extras vs R0: agg_kernel deleted;
//     aggregation FUSED into node_kernel via a 64KB LDS tile (each block
//     gathers its own 128 nodes from CSR, reading out_edges - ef). No agg
//     staging in d_out or ws. Node region written exactly once (node
//     epilogue), edge region exactly once (edge kernel). Edge kernel is
//     R0-verbatim minus the atomicAdd lines.

#define NN 50000
#define NE 600000
#define DD 128

typedef unsigned short u16;
typedef __attribute__((ext_vector_type(8))) short short8;
typedef __attribute__((ext_vector_type(4))) float f32x4;

__device__ __forceinline__ float bf2f(u16 x){
  union { unsigned u; float f; } c; c.u = ((unsigned)x) << 16; return c.f;
}
__device__ __forceinline__ u16 f2bf(float x){
  union { float f; unsigned u; } c; c.f = x;
  unsigned r = c.u + 0x7FFFu + ((c.u >> 16) & 1u);
  return (u16)(r >> 16);
}

// bf16 data: u16[2k] are bf16 values, exponent almost always in [0x7A,0x84]
// for N(0,1). f32 data: u16[2k] are low mantissa halves (~uniform bits),
// sane-exponent rate ~4%. 128 samples -> clean separation.
__global__ void detect_dtype(const u16* __restrict__ nf, int* __restrict__ flag){
  if (threadIdx.x == 0){
    int sane = 0;
    for (int k = 0; k < 128; ++k){
      int e = (nf[2*k] >> 7) & 0xFF;
      if (e >= 0x7A && e <= 0x84) ++sane;
    }
    *flag = (sane >= 64) ? 0 : 1;   // 0 = bf16, 1 = f32
  }
}

// Pack W[K][128] into MFMA B-fragment order (canonical bf16):
// P[((kc*8+t)*64+lane)*8 + j] = W[kc*32 + (lane>>4)*8 + j][t*16 + (lane&15)]
__global__ void pack_w(const void* __restrict__ Wv, u16* __restrict__ P, int KC,
                       const int* __restrict__ flag){
  int idx = blockIdx.x*256 + threadIdx.x;
  if (idx >= KC*8*64) return;
  const int isf32 = *flag;
  int lane = idx & 63, t = (idx>>6)&7, kc = idx>>9;
  int k0 = kc*32 + ((lane>>4)*8);
  int col = t*16 + (lane&15);
  short8 v;
  if (isf32){
    const float* W = (const float*)Wv;
    #pragma unroll
    for (int j=0;j<8;++j) v[j] = (short)f2bf(W[(size_t)(k0+j)*DD + col]);
  } else {
    const u16* W = (const u16*)Wv;
    #pragma unroll
    for (int j=0;j<8;++j) v[j] = (short)W[(size_t)(k0+j)*DD + col];
  }
  *reinterpret_cast<short8*>(P + (size_t)idx*8) = v;
}

// Convert 8 length-128 param vectors to canonical bf16.
__global__ void cvt_params(const void* p0, const void* p1, const void* p2,
                           const void* p3, const void* p4, const void* p5,
                           const void* p6, const void* p7,
                           u16* __restrict__ dst, const int* __restrict__ flag){
  const void* ps[8] = {p0,p1,p2,p3,p4,p5,p6,p7};
  int w = blockIdx.x, i = threadIdx.x;   // 8 blocks x 128 threads
  const int isf32 = *flag;
  dst[w*128 + i] = isf32 ? f2bf(((const float*)ps[w])[i]) : ((const u16*)ps[w])[i];
}

// ---- CSR build: counting sort of edges by receiver -------------------------

__global__ void hist_kernel(const int* __restrict__ rcv, int* __restrict__ deg){
  int i = blockIdx.x*256 + threadIdx.x;
  if (i < NE) atomicAdd(&deg[rcv[i]], 1);
}

// Single block of 1024 threads; each thread scans a contiguous chunk.
__global__ __launch_bounds__(1024)
void scan_kernel(const int* __restrict__ deg, int* __restrict__ rowstart,
                 int* __restrict__ cursor){
  __shared__ int buf[1024];
  const int t = threadIdx.x;
  const int C = (NN + 1023) / 1024;            // 49
  int lo = t * C;
  int hi = lo + C; if (hi > NN) hi = NN;
  int s = 0;
  for (int i = lo; i < hi; ++i) s += deg[i];
  buf[t] = s;
  __syncthreads();
  for (int off = 1; off < 1024; off <<= 1){
    int x = (t >= off) ? buf[t - off] : 0;
    __syncthreads();
    buf[t] += x;
    __syncthreads();
  }
  int run = buf[t] - s;                        // exclusive prefix of chunk
  for (int i = lo; i < hi; ++i){
    rowstart[i] = run; cursor[i] = run;
    run += deg[i];
  }
  if (t == 1023) rowstart[NN] = buf[1023];
}

__global__ void fill_kernel(const int* __restrict__ rcv, int* __restrict__ cursor,
                            int* __restrict__ eid){
  int i = blockIdx.x*256 + threadIdx.x;
  if (i < NE){
    int p = atomicAdd(&cursor[rcv[i]], 1);
    eid[p] = i;
  }
}

// ---- edge MLP (R0-verbatim minus atomics) ----------------------------------
// Per-wave tile: 32 rows x 128 cols. Block = 4 waves = 128 rows.
// LDS/wave: 8704 B (H bf16 32x136; reused as Y f32 16x132).

__global__ __launch_bounds__(256, 2)
void edge_kernel(const void* __restrict__ nfv, const void* __restrict__ efv,
                 const int* __restrict__ snd, const int* __restrict__ rcv,
                 const u16* __restrict__ P1, const u16* __restrict__ P2,
                 const u16* __restrict__ Pb,
                 void* __restrict__ outv, const int* __restrict__ flag)
{
  __shared__ __align__(16) char smem[4*8704];
  const int isf32 = *flag;
  const u16*   nf16 = (const u16*)nfv;   const float* nfF = (const float*)nfv;
  const u16*   ef16 = (const u16*)efv;   const float* efF = (const float*)efv;
  u16*   oute16 = (u16*)outv   + (size_t)NN*DD;   // edge block after node block
  float* outeF  = (float*)outv + (size_t)NN*DD;
  const u16* b1 = Pb;        const u16* b2  = Pb + 128;
  const u16* gam = Pb + 256; const u16* bet = Pb + 384;

  const int wave = threadIdx.x >> 6;
  const int lane = threadIdx.x & 63;
  const int q = lane >> 4, li = lane & 15;
  char* wbase = smem + wave*8704;
  u16*   Hs = (u16*)wbase;
  float* Ys = (float*)wbase;
  const int e0 = blockIdx.x*128 + wave*32;

  int eIdx[2], sIdx[2], rIdxA[2];
  #pragma unroll
  for (int mt=0; mt<2; ++mt){
    int e = e0 + mt*16 + li; if (e > NE-1) e = NE-1;
    eIdx[mt]=e; sIdx[mt]=snd[e]; rIdxA[mt]=rcv[e];
  }

  f32x4 acc[2][8];
  #pragma unroll
  for (int mt=0; mt<2; ++mt)
    #pragma unroll
    for (int t=0; t<8; ++t) acc[mt][t] = {0.f,0.f,0.f,0.f};

  // GEMM1: X[sender | receiver | edge] @ We1 -> H
  #pragma unroll
  for (int kc=0; kc<12; ++kc){
    const int off = q*8 + (kc&3)*32;
    short8 a[2];
    #pragma unroll
    for (int mt=0; mt<2; ++mt){
      size_t row = (kc < 8) ? (size_t)((kc<4)?sIdx[mt]:rIdxA[mt]) : (size_t)eIdx[mt];
      if (!isf32){
        const u16* base = (kc < 8) ? nf16 : ef16;
        a[mt] = *reinterpret_cast<const short8*>(base + row*DD + off);
      } else {
        const float* base = (kc < 8) ? nfF : efF;
        const float* src = base + row*DD + off;
        f32x4 u0 = *reinterpret_cast<const f32x4*>(src);
        f32x4 u1 = *reinterpret_cast<const f32x4*>(src + 4);
        short8 av;
        #pragma unroll
        for (int k=0;k<4;++k){ av[k]=(short)f2bf(u0[k]); av[4+k]=(short)f2bf(u1[k]); }
        a[mt] = av;
      }
    }
    const u16* bp = P1 + ((size_t)(kc*8)*64 + lane)*8;
    #pragma unroll
    for (int t=0; t<8; ++t){
      short8 b = *reinterpret_cast<const short8*>(bp + (size_t)t*512);
      acc[0][t] = __builtin_amdgcn_mfma_f32_16x16x32_bf16(a[0], b, acc[0][t],0,0,0);
      acc[1][t] = __builtin_amdgcn_mfma_f32_16x16x32_bf16(a[1], b, acc[1][t],0,0,0);
    }
  }

  // bias + relu -> H in LDS (bf16, rows=local edge, stride 136)
  #pragma unroll
  for (int t=0; t<8; ++t){
    float bv = bf2f(b1[t*16 + li]);
    #pragma unroll
    for (int mt=0; mt<2; ++mt){
      #pragma unroll
      for (int r=0; r<4; ++r){
        float v = acc[mt][t][r] + bv;
        v = v > 0.f ? v : 0.f;
        Hs[(size_t)(mt*16 + q*4 + r)*136 + t*16 + li] = f2bf(v);
      }
    }
  }
  __syncthreads();

  // GEMM2: H @ We2 -> Y
  f32x4 acc2[2][8];
  #pragma unroll
  for (int mt=0; mt<2; ++mt)
    #pragma unroll
    for (int t=0; t<8; ++t) acc2[mt][t] = {0.f,0.f,0.f,0.f};
  #pragma unroll
  for (int kc=0; kc<4; ++kc){
    short8 a[2];
    #pragma unroll
    for (int mt=0; mt<2; ++mt)
      a[mt] = *reinterpret_cast<const short8*>(Hs + (size_t)(mt*16+li)*136 + kc*32 + q*8);
    const u16* bp = P2 + ((size_t)(kc*8)*64 + lane)*8;
    #pragma unroll
    for (int t=0; t<8; ++t){
      short8 b = *reinterpret_cast<const short8*>(bp + (size_t)t*512);
      acc2[0][t] = __builtin_amdgcn_mfma_f32_16x16x32_bf16(a[0], b, acc2[0][t],0,0,0);
      acc2[1][t] = __builtin_amdgcn_mfma_f32_16x16x32_bf16(a[1], b, acc2[1][t],0,0,0);
    }
  }
  __syncthreads();

  // Epilogue: C-layout -> LDS f32 remap; LN; residual; store final output.
  const float inv = 0.0078125f;
  #pragma unroll
  for (int mt=0; mt<2; ++mt){
    #pragma unroll
    for (int t=0; t<8; ++t)
      #pragma unroll
      for (int r=0; r<4; ++r)
        Ys[(size_t)(q*4+r)*132 + t*16 + li] = acc2[mt][t][r];
    __syncthreads();

    const int rr = lane >> 2, qt = lane & 3, c0 = qt*32;
    const float* yrow = Ys + (size_t)rr*132 + c0;
    float sum = 0.f, sq = 0.f;
    #pragma unroll
    for (int i=0; i<8; ++i){
      f32x4 y = *reinterpret_cast<const f32x4*>(yrow + i*4);
      #pragma unroll
      for (int k=0; k<4; ++k){
        float v = y[k] + bf2f(b2[c0 + i*4 + k]);
        sum += v; sq += v*v;
      }
    }
    sum += __shfl_xor(sum, 1, 64); sq += __shfl_xor(sq, 1, 64);
    sum += __shfl_xor(sum, 2, 64); sq += __shfl_xor(sq, 2, 64);
    const float mu = sum * inv;
    const float var = sq * inv - mu*mu;
    const float rstd = rsqrtf(var + 1e-5f);

    const int e = e0 + mt*16 + rr;
    const bool valid = (e < NE);
    const int ec = valid ? e : NE-1;
    #pragma unroll
    for (int i=0; i<8; ++i){
      f32x4 y = *reinterpret_cast<const f32x4*>(yrow + i*4);
      f32x4 lv;
      #pragma unroll
      for (int k=0; k<4; ++k){
        int c = i*4 + k;
        float v = y[k] + bf2f(b2[c0+c]);
        lv[k] = (v - mu)*rstd*bf2f(gam[c0+c]) + bf2f(bet[c0+c]);
      }
      if (valid){
        if (!isf32){
          const u16* efr = ef16 + (size_t)ec*DD + c0;
          ushort4 st;
          #pragma unroll
          for (int k=0; k<4; ++k) ((u16*)&st)[k] = f2bf(lv[k] + bf2f(efr[i*4+k]));
          *reinterpret_cast<ushort4*>(oute16 + (size_t)ec*DD + c0 + i*4) = st;
        } else {
          const float* efr = efF + (size_t)ec*DD + c0;
          f32x4 st;
          #pragma unroll
          for (int k=0; k<4; ++k) st[k] = lv[k] + efr[i*4+k];
          *reinterpret_cast<f32x4*>(outeF + (size_t)ec*DD + c0 + i*4) = st;
        }
      }
    }
    __syncthreads();
  }
}

// ---- node MLP with FUSED gather aggregation --------------------------------
// Block = 4 waves = 128 nodes. Phase A: each wave gathers 32 of the block's
// nodes: aggL[ln][c] = sum_e (edge_out[e][c] - ef[e][c]) over the node's CSR
// list, into a 64KB LDS tile (XOR-swizzled: col ^ ((ln&7)<<2) to break the
// 16-way bank conflict on the column-slice GEMM reads). Phase B: MLP with
// A = [nf | aggL], R0-exact numerics (agg consumed as f32 -> f2bf).

__global__ __launch_bounds__(256, 2)
void node_kernel(const void* __restrict__ nfv, const void* __restrict__ efv,
                 const int* __restrict__ rowstart, const int* __restrict__ eid,
                 const u16* __restrict__ P1, const u16* __restrict__ P2,
                 const u16* __restrict__ Pb,
                 void* outv, const int* __restrict__ flag)
{
  __shared__ __align__(16) char smem[65536];    // aggL f32[128][128]
  float* aggL = (float*)smem;
  const int isf32 = *flag;
  const u16* nf16 = (const u16*)nfv;  const float* nfF = (const float*)nfv;
  u16* outn16 = (u16*)outv;           float* outnF = (float*)outv;
  const u16* b1 = Pb + 512;  const u16* b2  = Pb + 640;
  const u16* gam = Pb + 768; const u16* bet = Pb + 896;

  const int wave = threadIdx.x >> 6;
  const int lane = threadIdx.x & 63;
  const int q = lane >> 4, li = lane & 15;
  const int n0 = blockIdx.x*128;

  // ---- Phase A: gather this block's 128 agg rows into LDS ----
  {
    const int c0 = lane*2;
    for (int ln = wave; ln < 128; ln += 4){
      const int n = n0 + ln;
      float a0 = 0.f, a1 = 0.f;
      if (n < NN){
        const int beg = rowstart[n], end = rowstart[n+1];
        if (isf32){
          const float* oute = (const float*)outv + (size_t)NN*DD;
          const float* ef = (const float*)efv;
          for (int j = beg; j < end; ++j){
            int e = eid[j];
            float2 y = *reinterpret_cast<const float2*>(oute + (size_t)e*DD + c0);
            float2 r = *reinterpret_cast<const float2*>(ef   + (size_t)e*DD + c0);
            a0 += y.x - r.x; a1 += y.y - r.y;
          }
        } else {
          const u16* oute = (const u16*)outv + (size_t)NN*DD;
          const u16* ef = (const u16*)efv;
          for (int j = beg; j < end; ++j){
            int e = eid[j];
            unsigned y = *reinterpret_cast<const unsigned*>(oute + (size_t)e*DD + c0);
            unsigned r = *reinterpret_cast<const unsigned*>(ef   + (size_t)e*DD + c0);
            a0 += bf2f((u16)(y & 0xffffu)) - bf2f((u16)(r & 0xffffu));
            a1 += bf2f((u16)(y >> 16))     - bf2f((u16)(r >> 16));
          }
        }
      }
      const int sw = (ln & 7) << 2;
      float2 av; av.x = a0; av.y = a1;
      *reinterpret_cast<float2*>(&aggL[ln*128 + (c0 ^ sw)]) = av;
    }
  }
  __syncthreads();

  // ---- Phase B: node MLP (R0-exact numerics) ----
  char* wbase = smem + wave*8704;     // aliases aggL; safe after syncs below
  u16*   Hs = (u16*)wbase;
  float* Ys = (float*)wbase;

  int vIdx[2], lnr[2];
  #pragma unroll
  for (int mt=0; mt<2; ++mt){
    int v = n0 + wave*32 + mt*16 + li; if (v > NN-1) v = NN-1;
    vIdx[mt] = v; lnr[mt] = v - n0;
  }

  f32x4 acc[2][8];
  #pragma unroll
  for (int mt=0; mt<2; ++mt)
    #pragma unroll
    for (int t=0; t<8; ++t) acc[mt][t] = {0.f,0.f,0.f,0.f};

  // GEMM1: [nf | aggL] @ Wn1
  #pragma unroll
  for (int kc=0; kc<8; ++kc){
    short8 a[2];
    #pragma unroll
    for (int mt=0; mt<2; ++mt){
      if (kc < 4){
        if (!isf32){
          a[mt] = *reinterpret_cast<const short8*>(nf16 + (size_t)vIdx[mt]*DD + kc*32 + q*8);
        } else {
          const float* src = nfF + (size_t)vIdx[mt]*DD + kc*32 + q*8;
          f32x4 u0 = *reinterpret_cast<const f32x4*>(src);
          f32x4 u1 = *reinterpret_cast<const f32x4*>(src + 4);
          short8 av;
          #pragma unroll
          for (int k=0;k<4;++k){ av[k]=(short)f2bf(u0[k]); av[4+k]=(short)f2bf(u1[k]); }
          a[mt] = av;
        }
      } else {
        const int b = (kc-4)*32 + q*8;
        const int sw = (lnr[mt] & 7) << 2;
        const float* base = aggL + lnr[mt]*128;
        f32x4 u0 = *reinterpret_cast<const f32x4*>(&base[(b)   ^ sw]);
        f32x4 u1 = *reinterpret_cast<const f32x4*>(&base[(b+4) ^ sw]);
        short8 av;
        #pragma unroll
        for (int k=0; k<4; ++k){ av[k] = (short)f2bf(u0[k]); av[4+k] = (short)f2bf(u1[k]); }
        a[mt] = av;
      }
    }
    const u16* bp = P1 + ((size_t)(kc*8)*64 + lane)*8;
    #pragma unroll
    for (int t=0; t<8; ++t){
      short8 b = *reinterpret_cast<const short8*>(bp + (size_t)t*512);
      acc[0][t] = __builtin_amdgcn_mfma_f32_16x16x32_bf16(a[0], b, acc[0][t],0,0,0);
      acc[1][t] = __builtin_amdgcn_mfma_f32_16x16x32_bf16(a[1], b, acc[1][t],0,0,0);
    }
  }
  __syncthreads();   // all aggL reads done before Hs overwrites the tile

  #pragma unroll
  for (int t=0; t<8; ++t){
    float bv = bf2f(b1[t*16 + li]);
    #pragma unroll
    for (int mt=0; mt<2; ++mt){
      #pragma unroll
      for (int r=0; r<4; ++r){
        float v = acc[mt][t][r] + bv;
        v = v > 0.f ? v : 0.f;
        Hs[(size_t)(mt*16 + q*4 + r)*136 + t*16 + li] = f2bf(v);
      }
    }
  }
  __syncthreads();

  f32x4 acc2[2][8];
  #pragma unroll
  for (int mt=0; mt<2; ++mt)
    #pragma unroll
    for (int t=0; t<8; ++t) acc2[mt][t] = {0.f,0.f,0.f,0.f};
  #pragma unroll
  for (int kc=0; kc<4; ++kc){
    short8 a[2];
    #pragma unroll
    for (int mt=0; mt<2; ++mt)
      a[mt] = *reinterpret_cast<const short8*>(Hs + (size_t)(mt*16+li)*136 + kc*32 + q*8);
    const u16* bp = P2 + ((size_t)(kc*8)*64 + lane)*8;
    #pragma unroll
    for (int t=0; t<8; ++t){
      short8 b = *reinterpret_cast<const short8*>(bp + (size_t)t*512);
      acc2[0][t] = __builtin_amdgcn_mfma_f32_16x16x32_bf16(a[0], b, acc2[0][t],0,0,0);
      acc2[1][t] = __builtin_amdgcn_mfma_f32_16x16x32_bf16(a[1], b, acc2[1][t],0,0,0);
    }
  }
  __syncthreads();

  const float inv = 0.0078125f;
  #pragma unroll
  for (int mt=0; mt<2; ++mt){
    #pragma unroll
    for (int t=0; t<8; ++t)
      #pragma unroll
      for (int r=0; r<4; ++r)
        Ys[(size_t)(q*4+r)*132 + t*16 + li] = acc2[mt][t][r];
    __syncthreads();

    const int rr = lane >> 2, qt = lane & 3, c0 = qt*32;
    const float* yrow = Ys + (size_t)rr*132 + c0;
    float sum = 0.f, sq = 0.f;
    #pragma unroll
    for (int i=0; i<8; ++i){
      f32x4 y = *reinterpret_cast<const f32x4*>(yrow + i*4);
      #pragma unroll
      for (int k=0; k<4; ++k){
        float v = y[k] + bf2f(b2[c0 + i*4 + k]);
        sum += v; sq += v*v;
      }
    }
    sum += __shfl_xor(sum, 1, 64); sq += __shfl_xor(sq, 1, 64);
    sum += __shfl_xor(sum, 2, 64); sq += __shfl_xor(sq, 2, 64);
    const float mu = sum * inv;
    const float var = sq * inv - mu*mu;
    const float rstd = rsqrtf(var + 1e-5f);

    const int v = n0 + wave*32 + mt*16 + rr;
    const bool valid = (v < NN);
    const int vc = valid ? v : NN-1;
    #pragma unroll
    for (int i=0; i<8; ++i){
      f32x4 y = *reinterpret_cast<const f32x4*>(yrow + i*4);
      f32x4 lv;
      #pragma unroll
      for (int k=0; k<4; ++k){
        int c = i*4 + k;
        float vv = y[k] + bf2f(b2[c0+c]);
        lv[k] = (vv - mu)*rstd*bf2f(gam[c0+c]) + bf2f(bet[c0+c]);
      }
      if (valid){
        if (!isf32){
          const u16* nfr = nf16 + (size_t)vc*DD + c0;
          ushort4 st;
          #pragma unroll
          for (int k=0; k<4; ++k) ((u16*)&st)[k] = f2bf(lv[k] + bf2f(nfr[i*4+k]));
          *reinterpret_cast<ushort4*>(outn16 + (size_t)vc*DD + c0 + i*4) = st;
        } else {
          const float* nfr = nfF + (size_t)vc*DD + c0;
          f32x4 st;
          #pragma unroll
          for (int k=0; k<4; ++k) st[k] = lv[k] + nfr[i*4+k];
          *reinterpret_cast<f32x4*>(outnF + (size_t)vc*DD + c0 + i*4) = st;
        }
      }
    }
    __syncthreads();
  }
}

extern "C" void kernel_launch(void* const* d_in, const int* in_sizes, int n_in,
                              void* d_out, int out_size, void* d_ws, size_t ws_size,
                              hipStream_t stream)
{
  const void* nf  = d_in[0];
  const void* ef  = d_in[1];
  const int* snd  = (const int*)d_in[2];
  const int* rcv  = (const int*)d_in[3];

  // Compact workspace layout (~3.24 MB total, 4KB guard after eid):
  char* ws = (char*)d_ws;
  size_t off = 0;
  int* deg      = (int*)(ws + off); off += (size_t)NN*4;
  int* rowstart = (int*)(ws + off); off += (size_t)(NN+1)*4;
  int* cursor   = (int*)(ws + off); off += (size_t)NN*4;
  int* eid      = (int*)(ws + off); off += (size_t)NE*4;
  off += 4096;                                   // guard
  off = (off + 15) & ~(size_t)15;
  u16* Pe1 = (u16*)(ws + off); off += (size_t)384*DD*2;
  u16* Pe2 = (u16*)(ws + off); off += (size_t)128*DD*2;
  u16* Pn1 = (u16*)(ws + off); off += (size_t)256*DD*2;
  u16* Pn2 = (u16*)(ws + off); off += (size_t)128*DD*2;
  u16* Pb  = (u16*)(ws + off); off += (size_t)8*DD*2;
  int* flag = (int*)(ws + off); off += 16;

  detect_dtype<<<1, 64, 0, stream>>>((const u16*)nf, flag);
  hipMemsetAsync(deg, 0, (size_t)NN*4, stream);
  pack_w<<<24, 256, 0, stream>>>(d_in[4],  Pe1, 12, flag);
  pack_w<<<8,  256, 0, stream>>>(d_in[6],  Pe2, 4,  flag);
  pack_w<<<16, 256, 0, stream>>>(d_in[10], Pn1, 8,  flag);
  pack_w<<<8,  256, 0, stream>>>(d_in[12], Pn2, 4,  flag);
  cvt_params<<<8, 128, 0, stream>>>(d_in[5], d_in[7], d_in[8], d_in[9],
                                    d_in[11], d_in[13], d_in[14], d_in[15],
                                    Pb, flag);

  // CSR build (counting sort by receiver)
  hist_kernel<<<(NE+255)/256, 256, 0, stream>>>(rcv, deg);
  scan_kernel<<<1, 1024, 0, stream>>>(deg, rowstart, cursor);
  fill_kernel<<<(NE+255)/256, 256, 0, stream>>>(rcv, cursor, eid);

  // edge MLP (final output incl. residual), then node MLP with fused gather
  edge_kernel<<<(NE+127)/128, 256, 0, stream>>>(nf, ef, snd, rcv, Pe1, Pe2,
                                                Pb, d_out, flag);
  node_kernel<<<(NN+127)/128, 256, 0, stream>>>(nf, ef, rowstart, eid,
                                                Pn1, Pn2, Pb, d_out, flag);
}